// Round 7
// baseline (366.264 us; speedup 1.0000x reference)
//
#include <hip/hip_runtime.h>
#include <stdint.h>

typedef float f32x16 __attribute__((ext_vector_type(16)));
typedef int   i32x4 __attribute__((ext_vector_type(4)));
typedef int   i32x8 __attribute__((ext_vector_type(8)));

__device__ __forceinline__ float amax4(float4 v) {
  return fmaxf(fmaxf(fabsf(v.x), fabsf(v.y)), fmaxf(fabsf(v.z), fabsf(v.w)));
}

// ---------------------------------------------------------------------------
// Fused amax + quant, one kernel, device-scope arrive/spin barrier.
// r4's failure causes fixed:
//  - BOTH phases are 4-wide MLP (r4's 1-deep loops -> latency-bound 530 GB/s)
//  - co-residency margin: grid 1280, ~30 VGPR, no meaningful LDS ->
//    capacity 8 blocks/CU x 256 CU = 2048 >> 1280 (r4 ran at exact capacity)
// Exact sizing: 1024 x-blocks / 256 w-blocks -> 16 float4/thread each
// (4 iterations of 4-wide, no tail).
// sync[0]/sync[1] = amax bits (atomicMax on non-negative f32 bits == fp max),
// sync[2] = arrival counter; all zeroed by the async memset.
// Phase 2 re-reads its slice (L3-hot: 84 MB << 256 MB Infinity Cache).
// Quantization bit-exact vs ml_dtypes: true f32 division (NOT recip-mul:
// a 1-ulp quotient flip at an fp8 RNE boundary would exceed threshold over
// 21M elements) + RNE v_cvt_pk_fp8_f32 (OCP e4m3fn).
// ---------------------------------------------------------------------------
__global__ __launch_bounds__(256) void amax_quant_kernel(
    const float* __restrict__ x, unsigned char* __restrict__ qx, int nx4,
    const float* __restrict__ w, unsigned char* __restrict__ qw, int nw4,
    int xblocks, int nblocks, unsigned* __restrict__ sync) {
  const float4* src;
  unsigned* dst;
  int n4, j0, stride, slot;
  if ((int)blockIdx.x < xblocks) {
    src = (const float4*)x; dst = (unsigned*)qx; n4 = nx4; slot = 0;
    j0 = blockIdx.x * blockDim.x + threadIdx.x;
    stride = xblocks * blockDim.x;
  } else {
    src = (const float4*)w; dst = (unsigned*)qw; n4 = nw4; slot = 1;
    j0 = (blockIdx.x - xblocks) * blockDim.x + threadIdx.x;
    stride = (gridDim.x - xblocks) * blockDim.x;
  }

  // Phase 1: amax over my slice, 4 independent loads in flight.
  float m0 = 0.f, m1 = 0.f, m2 = 0.f, m3 = 0.f;
  int j = j0;
  for (; j + 3 * stride < n4; j += 4 * stride) {
    float4 v0 = src[j];
    float4 v1 = src[j + stride];
    float4 v2 = src[j + 2 * stride];
    float4 v3 = src[j + 3 * stride];
    m0 = fmaxf(m0, amax4(v0));
    m1 = fmaxf(m1, amax4(v1));
    m2 = fmaxf(m2, amax4(v2));
    m3 = fmaxf(m3, amax4(v3));
  }
  for (; j < n4; j += stride) m0 = fmaxf(m0, amax4(src[j]));
  float m = fmaxf(fmaxf(m0, m1), fmaxf(m2, m3));
#pragma unroll
  for (int off = 32; off; off >>= 1)
    m = fmaxf(m, __shfl_down(m, off, 64));
  __shared__ float red[4];
  __shared__ float s_inv;
  const int lane = threadIdx.x & 63;
  const int wv = threadIdx.x >> 6;
  if (lane == 0) red[wv] = m;
  __syncthreads();

  // Arrive (release) + spin (acquire), thread 0 only; broadcast via LDS.
  if (threadIdx.x == 0) {
    m = fmaxf(fmaxf(red[0], red[1]), fmaxf(red[2], red[3]));
    atomicMax((int*)sync + slot, (int)__float_as_uint(m));
    __threadfence();
    __hip_atomic_fetch_add(sync + 2, 1u, __ATOMIC_ACQ_REL,
                           __HIP_MEMORY_SCOPE_AGENT);
    while (__hip_atomic_load(sync + 2, __ATOMIC_ACQUIRE,
                             __HIP_MEMORY_SCOPE_AGENT) < (unsigned)nblocks)
      __builtin_amdgcn_s_sleep(8);
    const float amax = __uint_as_float(__hip_atomic_load(
        sync + slot, __ATOMIC_ACQUIRE, __HIP_MEMORY_SCOPE_AGENT));
    s_inv = fmaxf(amax / 448.0f, 1e-12f);
  }
  __syncthreads();

  // Phase 2: quantize my slice (L3-hot), 4-wide MLP.
  const float inv_scale = s_inv;
  j = j0;
  for (; j + 3 * stride < n4; j += 4 * stride) {
    float4 v0 = src[j];
    float4 v1 = src[j + stride];
    float4 v2 = src[j + 2 * stride];
    float4 v3 = src[j + 3 * stride];
#pragma unroll
    for (int u = 0; u < 4; u++) {
      float4 v = (u == 0) ? v0 : (u == 1) ? v1 : (u == 2) ? v2 : v3;
      float a0 = v.x / inv_scale;
      float a1 = v.y / inv_scale;
      float a2 = v.z / inv_scale;
      float a3 = v.w / inv_scale;
      int p = 0;
      p = __builtin_amdgcn_cvt_pk_fp8_f32(a0, a1, p, false);
      p = __builtin_amdgcn_cvt_pk_fp8_f32(a2, a3, p, true);
      dst[j + u * stride] = (unsigned)p;
    }
  }
  for (; j < n4; j += stride) {
    float4 v = src[j];
    float a0 = v.x / inv_scale;
    float a1 = v.y / inv_scale;
    float a2 = v.z / inv_scale;
    float a3 = v.w / inv_scale;
    int p = 0;
    p = __builtin_amdgcn_cvt_pk_fp8_f32(a0, a1, p, false);
    p = __builtin_amdgcn_cvt_pk_fp8_f32(a2, a3, p, true);
    dst[j] = (unsigned)p;
  }
}

// ---------------------------------------------------------------------------
// MX-scaled fp8 GEMM (unit scales) — r6 kernel VERBATIM (proven 44.4 us,
// 1549 TF): 256x128 block tile, BK=128, 4 waves 2x2 each owning 128x64 via
// 4x2 of mfma_scale_f32_32x32x64_f8f6f4.
// A-operand layout (MX rule): lane l holds A[row=l&31][k=(l>>5)*32+j].
// C/D layout (m74/m101): col=lane&31, row=(reg&3)+8*(reg>>2)+4*(lane>>5).
// LDS swizzle: store global 16B chunk c_g = c_s ^ (row&7) (global-source
// permute; global_load_lds dest must stay wave_base+lane*16); fragment reads
// xor identically -> uniform 8 dwords/bank (structural floor, 3.15e6 cnt).
// ---------------------------------------------------------------------------
#define BM 256
#define BN 128
#define BK 128

__device__ __forceinline__ void load_lds16(const void* g, void* l) {
  __builtin_amdgcn_global_load_lds(
      (const __attribute__((address_space(1))) unsigned int*)g,
      (__attribute__((address_space(3))) unsigned int*)l, 16, 0, 0);
}

__global__ __launch_bounds__(256, 2) void gemm_fp8_kernel(
    const unsigned char* __restrict__ Aq,   // [T,K] fp8
    const unsigned char* __restrict__ Bq,   // [N,K] fp8 (W quantized, row-major)
    const float* __restrict__ bias,         // [N]
    const unsigned* __restrict__ amax2,     // [0]=amax(x), [1]=amax(w) bits
    float* __restrict__ out,                // [T,N]
    int T, int N, int K) {
  __shared__ __align__(16) unsigned char sA[BM * BK];  // 32 KB
  __shared__ __align__(16) unsigned char sB[BN * BK];  // 16 KB

  const int tid = threadIdx.x;
  const int lane = tid & 63;
  const int wave = tid >> 6;
  const int wm = (wave >> 1) * 128;  // wave row offset in tile
  const int wn = (wave & 1) * 64;    // wave col offset in tile
  const long m0 = (long)blockIdx.y * BM;
  const long n0 = (long)blockIdx.x * BN;

  f32x16 acc[4][2];
#pragma unroll
  for (int i = 0; i < 4; i++)
#pragma unroll
    for (int j = 0; j < 2; j++)
#pragma unroll
      for (int r = 0; r < 16; r++) acc[i][j][r] = 0.f;

  // Staging: 32 rows per 4KB round (8 rounds A, 4 rounds B).
  const int row_s = tid >> 3;
  const int scol = ((tid & 7) ^ (row_s & 7)) << 4;
  const int o = tid * 16;  // LDS offset within a round
  const unsigned char* aBase = Aq + (m0 + row_s) * (long)K + scol;
  const unsigned char* bBase = Bq + (n0 + row_s) * (long)K + scol;

  const int lr = lane & 31;   // row within 32x32 tile
  const int kh = lane >> 5;   // k-half selector
  const int swz = lr & 7;     // xor swizzle (row&7); wm/wn/mt*32 vanish mod 8

  for (int k0 = 0; k0 < K; k0 += BK) {
#pragma unroll
    for (int r = 0; r < 8; r++)
      load_lds16(aBase + (long)r * 32 * K + k0, sA + r * 4096 + o);
#pragma unroll
    for (int r = 0; r < 4; r++)
      load_lds16(bBase + (long)r * 32 * K + k0, sB + r * 4096 + o);
    __syncthreads();  // staging complete

#pragma unroll
    for (int s = 0; s < 2; s++) {      // two K=64 slabs per k0
      const int kc0 = s * 4 + kh * 2;  // first global 16B chunk of this lane
      const int c0 = (kc0 ^ swz) << 4;
      const int c1 = ((kc0 + 1) ^ swz) << 4;
      i32x8 af[4], bf[2];
#pragma unroll
      for (int mt = 0; mt < 4; mt++) {
        const unsigned char* p = sA + (wm + mt * 32 + lr) * BK;
        i32x4 lo = *(const i32x4*)(p + c0);
        i32x4 hi = *(const i32x4*)(p + c1);
        af[mt] = (i32x8){lo.x, lo.y, lo.z, lo.w, hi.x, hi.y, hi.z, hi.w};
      }
#pragma unroll
      for (int nt = 0; nt < 2; nt++) {
        const unsigned char* p = sB + (wn + nt * 32 + lr) * BK;
        i32x4 lo = *(const i32x4*)(p + c0);
        i32x4 hi = *(const i32x4*)(p + c1);
        bf[nt] = (i32x8){lo.x, lo.y, lo.z, lo.w, hi.x, hi.y, hi.z, hi.w};
      }
#pragma unroll
      for (int mt = 0; mt < 4; mt++)
#pragma unroll
        for (int nt = 0; nt < 2; nt++)
          acc[mt][nt] = __builtin_amdgcn_mfma_scale_f32_32x32x64_f8f6f4(
              af[mt], bf[nt], acc[mt][nt],
              /*cbsz=fp8*/ 0, /*blgp=fp8*/ 0,
              /*opsel_a*/ 0, 0x7f7f7f7f, /*opsel_b*/ 0, 0x7f7f7f7f);
    }
    __syncthreads();  // LDS reads done before next stage overwrites
  }

  // Epilogue.
  const float sx = fmaxf(__uint_as_float(amax2[0]) / 448.0f, 1e-12f);
  const float sw = fmaxf(__uint_as_float(amax2[1]) / 448.0f, 1e-12f);
  const float scale = sx * sw;
  const float bv0 = bias[n0 + wn + lr];
  const float bv1 = bias[n0 + wn + 32 + lr];
#pragma unroll
  for (int mt = 0; mt < 4; mt++) {
#pragma unroll
    for (int reg = 0; reg < 16; reg++) {
      const long row =
          m0 + wm + mt * 32 + (reg & 3) + 8 * (reg >> 2) + 4 * kh;
      float* orow = out + row * (long)N + n0 + wn + lr;
      orow[0] = acc[mt][0][reg] * scale + bv0;
      orow[32] = acc[mt][1][reg] * scale + bv1;
    }
  }
}

// ---------------------------------------------------------------------------
extern "C" void kernel_launch(void* const* d_in, const int* in_sizes, int n_in,
                              void* d_out, int out_size, void* d_ws, size_t ws_size,
                              hipStream_t stream) {
  const float* x = (const float*)d_in[0];       // [4,2048,2048] f32
  const float* w = (const float*)d_in[1];       // [2048,2048]   f32
  const float* bias = (const float*)d_in[2];    // [2048]        f32
  float* out = (float*)d_out;

  const int N = in_sizes[2];        // 2048
  const int K = in_sizes[1] / N;    // 2048
  const int T = in_sizes[0] / K;    // 8192

  unsigned* sync = (unsigned*)d_ws;                // [0..1] amax, [2] counter
  unsigned char* qx = (unsigned char*)d_ws + 256;  // T*K fp8
  unsigned char* qw = qx + (size_t)T * K;          // N*K fp8

  hipMemsetAsync(d_ws, 0, 256, stream);  // zero amax slots + barrier counter

  // 1024 x-blocks + 256 w-blocks = 1280; both partitions get exactly
  // 16 float4/thread. Capacity at ~30 VGPR is 8 blocks/CU = 2048 >> 1280.
  const int XB = 1024;
  const int WB = 256;
  amax_quant_kernel<<<XB + WB, 256, 0, stream>>>(
      x, qx, T * K / 4, w, qw, N * K / 4, XB, XB + WB, sync);

  dim3 grid(N / BN, T / BM);
  gemm_fp8_kernel<<<grid, 256, 0, stream>>>(qx, qw, bias, sync, out, T, N, K);
}